// Round 3
// baseline (4375.767 us; speedup 1.0000x reference)
//
#include <hip/hip_runtime.h>
#include <hip/hip_bf16.h>

typedef __bf16 bf16x8 __attribute__((ext_vector_type(8)));
typedef float f32x16 __attribute__((ext_vector_type(16)));

#define HSZ (1024*512)      // h/c slot elems
#define WSZ (2048*512)      // weight matrix elems

__device__ __forceinline__ float fsig(float x){ return 1.0f/(1.0f+__expf(-x)); }
__device__ __forceinline__ float ftanh(float x){ return 1.0f - 2.0f/(__expf(2.0f*x)+1.0f); }

__device__ __forceinline__ void gload16(const void* g, void* l){
  __builtin_amdgcn_global_load_lds((const __attribute__((address_space(1))) void*)g,
                                   (__attribute__((address_space(3))) void*)l, 16, 0, 0);
}

// fp32 -> bf16 (RNE) converter
__global__ void f2b4(const float4* __restrict__ src, ushort4* __restrict__ dst, int n4){
  int i = blockIdx.x*blockDim.x + threadIdx.x;
  if (i < n4){
    float4 v = src[i];
    __hip_bfloat16 a=__float2bfloat16(v.x), b=__float2bfloat16(v.y), c=__float2bfloat16(v.z), d=__float2bfloat16(v.w);
    ushort4 r;
    r.x = *reinterpret_cast<ushort*>(&a);
    r.y = *reinterpret_cast<ushort*>(&b);
    r.z = *reinterpret_cast<ushort*>(&c);
    r.w = *reinterpret_cast<ushort*>(&d);
    dst[i] = r;
  }
}

__global__ void init_decin(const float* __restrict__ x, float* __restrict__ di){
  int i = blockIdx.x*blockDim.x + threadIdx.x;
  if (i < 2048){ int m = i >> 1, j = i & 1; di[i] = x[(size_t)63*4096 + m*4 + j]; }
}

// Wcomb[n][k] = dec_Wih0[n][0]*lin_W[0][k] + dec_Wih0[n][1]*lin_W[1][k]  (bf16)
__global__ void make_wcomb(const float* __restrict__ dWih0, const float* __restrict__ linW,
                           ushort* __restrict__ wc){
  int i = blockIdx.x*blockDim.x + threadIdx.x;
  if (i < 2048*512){
    int n = i >> 9, k = i & 511;
    float v = dWih0[n*2]*linW[k] + dWih0[n*2+1]*linW[512+k];
    __hip_bfloat16 b = __float2bfloat16(v);
    wc[i] = *reinterpret_cast<ushort*>(&b);
  }
}

// combined biases: rows 0-2 enc l0-l2; 3 dec l0 (t=0); 4 dec l0 (t>=1, +Wih0@lin_b); 5,6 dec l1,l2
__global__ void prep_bias(const float* ebih0, const float* ebhh0,
                          const float* ebih, const float* ebhh,
                          const float* dbih0, const float* dbhh0,
                          const float* dbih, const float* dbhh,
                          const float* dWih0, const float* linb, float* bout){
  int n = blockIdx.x*blockDim.x + threadIdx.x;
  if (n >= 2048) return;
  bout[n]        = ebih0[n] + ebhh0[n];
  bout[2048+n]   = ebih[n] + ebhh[n];
  bout[2*2048+n] = ebih[2048+n] + ebhh[2048+n];
  float d0 = dbih0[n] + dbhh0[n];
  bout[3*2048+n] = d0;
  bout[4*2048+n] = d0 + dWih0[n*2]*linb[0] + dWih0[n*2+1]*linb[1];
  bout[5*2048+n] = dbih[n] + dbhh[n];
  bout[6*2048+n] = dbih[2048+n] + dbhh[2048+n];
}

struct CellPar {
  const ushort* A0; const ushort* W0;   // bf16 segment 0 (A:[1024][512], W:[2048][512])
  const ushort* A1; const ushort* W1;   // bf16 segment 1 (null if absent)
  const float*  xs; const float* Ws; int ks;  // small-K fp32 part
  const float*  bias;                   // combined bias [2048]
  float* c; ushort* h_out;
};

// WG tile: 64 batch x 128 gate-rows (h-major: row = h_local*4 + gate), grid (16,16).
// 4 waves arranged 2(batch) x 2(gate): wave tile 32 x 64 via mfma_f32_32x32x16_bf16
// (1 A-frag + 2 B-frags per k16 -> 0.75 KB LDS-read per 16-KFLOP unit).
// 3 LDS buffers (24KB each), 1 barrier/K-step, counted vmcnt(6), setprio(1) on MFMA.
__device__ __forceinline__ void cell_body(const CellPar P, char* ldsb)
{
  const int tid  = threadIdx.x;
  const int m0   = blockIdx.x << 6;    // 64 batch rows
  const int h0   = blockIdx.y << 5;    // 32 h columns (=128 gate rows)
  const int w    = tid >> 6, lane = tid & 63;
  const int wm   = w >> 1, wn = w & 1;
  const int l31  = lane & 31, lhi = lane >> 5;
  const int srow = lane >> 3, scch = lane & 7;

  const ushort* Aseg[2] = { P.A0, P.A1 };
  const ushort* Wseg[2] = { P.W0, P.W1 };
  const int nt = (P.A1 != nullptr) ? 16 : 8;   // K-steps of 64 (8 per 512-K segment)

  auto stage = [&](int buf, int it){
    const int seg = it >> 3;
    const int k0  = (it & 7) << 6;
    const ushort* A  = Aseg[seg];
    const ushort* Wt = Wseg[seg];
    ushort* Als = (ushort*)(ldsb + buf*24576);
    ushort* Bls = Als + 4096;                   // +8KB
    #pragma unroll
    for (int q = 0; q < 2; ++q){                // A: 64 rows, 2 instr/wave
      const int base = (w<<4) + (q<<3);
      const int r  = base + srow;
      const int sw = (scch ^ (r & 7)) << 3;     // pre-swizzled source chunk
      gload16(A + (size_t)(m0 + r)*512 + k0 + sw, Als + base*64);
    }
    #pragma unroll
    for (int q = 0; q < 4; ++q){                // B: 128 rows (h-major), 4 instr/wave
      const int base = (w<<5) + (q<<3);
      const int r  = base + srow;
      const int g = r & 3, hh = r >> 2;
      const int sw = (scch ^ (r & 7)) << 3;
      gload16(Wt + ((size_t)(g<<9) + h0 + hh)*512 + k0 + sw, Bls + base*64);
    }
  };

  f32x16 acc0 = {0.f}, acc1 = {0.f};
  #pragma unroll
  for (int i = 0; i < 16; ++i){ acc0[i] = 0.f; acc1[i] = 0.f; }

  stage(0, 0);
  stage(1, 1);
  for (int it = 0; it < nt; ++it){
    const int cur = it % 3;
    if (it == nt - 1) asm volatile("s_waitcnt vmcnt(0)" ::: "memory");
    else              asm volatile("s_waitcnt vmcnt(6)" ::: "memory");
    __builtin_amdgcn_s_barrier();                // stage(it) fully landed, prev reads done
    __builtin_amdgcn_sched_barrier(0);
    if (it + 2 < nt) stage((it + 2) % 3, it + 2);
    const ushort* Als = (const ushort*)(ldsb + cur*24576);
    const ushort* Bls = Als + 4096;
    const int arow  = (wm<<5) + l31;
    const int brow0 = (wn<<6) + l31;
    const int brow1 = brow0 + 32;
    __builtin_amdgcn_s_setprio(1);
    #pragma unroll
    for (int kc = 0; kc < 4; ++kc){
      const int ch = (kc<<1) + lhi;
      bf16x8 av  = *(const bf16x8*)(Als + arow*64  + ((ch ^ (arow  & 7)) << 3));
      bf16x8 bv0 = *(const bf16x8*)(Bls + brow0*64 + ((ch ^ (brow0 & 7)) << 3));
      acc0 = __builtin_amdgcn_mfma_f32_32x32x16_bf16(av, bv0, acc0, 0, 0, 0);
      bf16x8 bv1 = *(const bf16x8*)(Bls + brow1*64 + ((ch ^ (brow1 & 7)) << 3));
      acc1 = __builtin_amdgcn_mfma_f32_32x32x16_bf16(av, bv1, acc1, 0, 0, 0);
    }
    __builtin_amdgcn_s_setprio(0);
  }

  // ---- epilogue: gate exchange through LDS, then pointwise ----
  __builtin_amdgcn_s_barrier();                  // all LDS reads done; reuse buffers
  float* Gls = (float*)ldsb;                     // [64 batch][128 gate-rows] f32 = 32KB
  #pragma unroll
  for (int nf = 0; nf < 2; ++nf){
    const f32x16 a = nf ? acc1 : acc0;
    const int grow = (wn<<6) + (nf<<5) + l31;
    #pragma unroll
    for (int reg = 0; reg < 16; ++reg){
      const int bl = (wm<<5) + (reg & 3) + ((reg >> 2) << 3) + (lhi << 2);
      Gls[bl*128 + grow] = a[reg];
    }
  }
  __syncthreads();

  const int m_l = tid >> 2, hq = tid & 3;
  const int m = m0 + m_l;
  float xv[4];
  if (P.ks > 0){
    #pragma unroll
    for (int k = 0; k < 4; ++k) xv[k] = (k < P.ks) ? P.xs[(size_t)m*P.ks + k] : 0.f;
  }
  #pragma unroll
  for (int j = 0; j < 8; ++j){
    const int h_l = (hq<<3) + j;
    const int h   = h0 + h_l;
    float gv[4];
    #pragma unroll
    for (int g = 0; g < 4; ++g){
      float t_ = Gls[m_l*128 + (h_l<<2) + g] + P.bias[(g<<9) + h];
      if (P.ks > 0){
        #pragma unroll
        for (int k = 0; k < 4; ++k)
          if (k < P.ks) t_ += xv[k] * P.Ws[(size_t)((g<<9) + h)*P.ks + k];
      }
      gv[g] = t_;
    }
    const float iG = fsig(gv[0]);
    const float fG = fsig(gv[1]);
    const float gG = ftanh(gv[2]);
    const float oG = fsig(gv[3]);
    const size_t off = (size_t)m*512 + h;
    const float cn = fG*P.c[off] + iG*gG;
    P.c[off] = cn;
    const float hv = oG*ftanh(cn);
    __hip_bfloat16 hb = __float2bfloat16(hv);
    P.h_out[off] = *reinterpret_cast<const ushort*>(&hb);
  }
}

__global__ __launch_bounds__(256) void cell_k(CellPar P){
  __shared__ char lds[73728];
  cell_body(P, lds);
}

struct EncPack {
  const float* x; const float* Wih0f;
  const ushort* eWhh0; const ushort* eWih; const ushort* eWhh;
  const float* biases; ushort* hbuf; float* cbuf; int s;
};

// fused encoder wavefront step: blockIdx.z = layer, t = s - l
__global__ __launch_bounds__(256) void enc_step(EncPack E){
  __shared__ char lds[73728];
  const int l = blockIdx.z;
  const int t = E.s - l;
  if (t < 0 || t > 63) return;
  const int p = E.s & 1;
  CellPar P;
  if (l == 0){
    P = { E.hbuf + (size_t)(p^1)*HSZ, E.eWhh0,
          nullptr, nullptr,
          E.x + (size_t)t*4096, E.Wih0f, 4,
          E.biases, E.cbuf, E.hbuf + (size_t)p*HSZ };
  } else {
    P = { E.hbuf + (size_t)(2*(l-1) + (p^1))*HSZ, E.eWih + (size_t)(l-1)*WSZ,
          E.hbuf + (size_t)(2*l + (p^1))*HSZ,     E.eWhh + (size_t)(l-1)*WSZ,
          nullptr, nullptr, 0,
          E.biases + l*2048, E.cbuf + (size_t)l*HSZ, E.hbuf + (size_t)(2*l + p)*HSZ };
  }
  cell_body(P, lds);
}

// batched final linear over all 32 steps: rows = 32*1024
__global__ __launch_bounds__(256) void out_linear(const ushort* __restrict__ h2,
    const float* __restrict__ linW, const float* __restrict__ linb, float* __restrict__ outp){
  int tid = threadIdx.x, w = tid >> 6, lane = tid & 63;
  int rbase = blockIdx.x*32 + w*8;
  for (int r = 0; r < 8; ++r){
    int m = rbase + r;
    float p0 = 0.f, p1 = 0.f;
    #pragma unroll
    for (int kk = 0; kk < 8; ++kk){
      int k = lane + kk*64;
      float hv = __uint_as_float(((unsigned)h2[(size_t)m*512 + k]) << 16);
      p0 += hv * linW[k];
      p1 += hv * linW[512 + k];
    }
    #pragma unroll
    for (int off = 32; off > 0; off >>= 1){
      p0 += __shfl_down(p0, off);
      p1 += __shfl_down(p1, off);
    }
    if (lane == 0){
      outp[(size_t)m*2]   = p0 + linb[0];
      outp[(size_t)m*2+1] = p1 + linb[1];
    }
  }
}

// fallback per-step linear (small-ws path): writes out slice + dec_in
__global__ __launch_bounds__(256) void dec_linear(const ushort* __restrict__ h2,
    const float* __restrict__ linW, const float* __restrict__ linb,
    float* __restrict__ outp, float* __restrict__ di){
  int tid = threadIdx.x, w = tid >> 6, lane = tid & 63;
  int mbase = blockIdx.x*32 + w*8;
  for (int r = 0; r < 8; ++r){
    int m = mbase + r;
    float p0 = 0.f, p1 = 0.f;
    #pragma unroll
    for (int kk = 0; kk < 8; ++kk){
      int k = lane + kk*64;
      float hv = __uint_as_float(((unsigned)h2[(size_t)m*512 + k]) << 16);
      p0 += hv * linW[k];
      p1 += hv * linW[512 + k];
    }
    #pragma unroll
    for (int off = 32; off > 0; off >>= 1){
      p0 += __shfl_down(p0, off);
      p1 += __shfl_down(p1, off);
    }
    if (lane == 0){
      float o0 = p0 + linb[0], o1 = p1 + linb[1];
      outp[m*2]   = o0; outp[m*2+1] = o1;
      di[m*2]     = o0; di[m*2+1]   = o1;
    }
  }
}

extern "C" void kernel_launch(void* const* d_in, const int* in_sizes, int n_in,
                              void* d_out, int out_size, void* d_ws, size_t ws_size,
                              hipStream_t stream)
{
  const float* x        = (const float*)d_in[0];
  const float* enc_Wih0 = (const float*)d_in[1];
  const float* enc_Whh0 = (const float*)d_in[2];
  const float* enc_bih0 = (const float*)d_in[3];
  const float* enc_bhh0 = (const float*)d_in[4];
  const float* enc_Wih  = (const float*)d_in[5];
  const float* enc_Whh  = (const float*)d_in[6];
  const float* enc_bih  = (const float*)d_in[7];
  const float* enc_bhh  = (const float*)d_in[8];
  const float* dec_Wih0 = (const float*)d_in[9];
  const float* dec_Whh0 = (const float*)d_in[10];
  const float* dec_bih0 = (const float*)d_in[11];
  const float* dec_bhh0 = (const float*)d_in[12];
  const float* dec_Wih  = (const float*)d_in[13];
  const float* dec_Whh  = (const float*)d_in[14];
  const float* dec_bih  = (const float*)d_in[15];
  const float* dec_bhh  = (const float*)d_in[16];
  const float* lin_W    = (const float*)d_in[17];
  const float* lin_b    = (const float*)d_in[18];

  // big path needs: 2*(11W + 6HS + 32HS) + 4*(3HS + 2048 + 7*2048) bytes = 69,271,552
  const bool big = ws_size >= 69271552ull;

  ushort* wb     = (ushort*)d_ws;
  ushort* eWhh0b = wb;
  ushort* eWihb  = wb + (size_t)WSZ;
  ushort* eWhhb  = wb + 3*(size_t)WSZ;
  ushort* dWhh0b = wb + 5*(size_t)WSZ;
  ushort* dWihb  = wb + 6*(size_t)WSZ;
  ushort* dWhhb  = wb + 8*(size_t)WSZ;
  ushort* wcombb = wb + 10*(size_t)WSZ;                   // big only
  ushort* hbuf   = wb + (big ? 11 : 10)*(size_t)WSZ;      // 6 HSZ (3 layers x 2 slots)
  ushort* h2hist = hbuf + 6*(size_t)HSZ;                  // big: 32 HSZ
  float*  cbuf   = (float*)(h2hist + (big ? 32*(size_t)HSZ : 0));
  float*  dec_in = cbuf + 3*(size_t)HSZ;                  // 2048
  float*  biases = dec_in + 2048;                         // 7*2048

  hipMemsetAsync(hbuf, 0, 6*(size_t)HSZ*2, stream);
  hipMemsetAsync(cbuf, 0, 3*(size_t)HSZ*4, stream);

  const int thr = 256;
  {
    struct { const float* s; ushort* d; size_t n; } cv[6] = {
      {enc_Whh0, eWhh0b, WSZ}, {enc_Wih, eWihb, 2*(size_t)WSZ}, {enc_Whh, eWhhb, 2*(size_t)WSZ},
      {dec_Whh0, dWhh0b, WSZ}, {dec_Wih, dWihb, 2*(size_t)WSZ}, {dec_Whh, dWhhb, 2*(size_t)WSZ},
    };
    for (int i = 0; i < 6; ++i){
      int n4 = (int)(cv[i].n/4);
      f2b4<<<(n4+thr-1)/thr, thr, 0, stream>>>((const float4*)cv[i].s, (ushort4*)cv[i].d, n4);
    }
  }
  if (big) make_wcomb<<<4096, thr, 0, stream>>>(dec_Wih0, lin_W, wcombb);
  prep_bias<<<8, thr, 0, stream>>>(enc_bih0, enc_bhh0, enc_bih, enc_bhh,
                                   dec_bih0, dec_bhh0, dec_bih, dec_bhh,
                                   dec_Wih0, lin_b, biases);
  init_decin<<<8, thr, 0, stream>>>(x, dec_in);

  const dim3 cgrid(16, 16), cblk(256);

  // ---- encoder: fused wavefront steps ----
  for (int s = 0; s < 66; ++s){
    EncPack E = { x, enc_Wih0, eWhh0b, eWihb, eWhhb, biases, hbuf, cbuf, s };
    enc_step<<<dim3(16,16,3), cblk, 0, stream>>>(E);
  }

  // encoder-final slots: layer l written at step 63+l -> slot (63+l)&1
  int cur0 = 1, cur1 = 0, cur2 = 1;

  if (big){
    for (int t = 0; t < 32; ++t){
      CellPar P0;
      if (t == 0)
        P0 = { hbuf + (size_t)cur0*HSZ, dWhh0b, nullptr, nullptr,
               dec_in, dec_Wih0, 2, biases + 3*2048, cbuf, hbuf + (size_t)(cur0^1)*HSZ };
      else
        P0 = { h2hist + (size_t)(t-1)*HSZ, wcombb, hbuf + (size_t)cur0*HSZ, dWhh0b,
               nullptr, nullptr, 0, biases + 4*2048, cbuf, hbuf + (size_t)(cur0^1)*HSZ };
      cell_k<<<cgrid, cblk, 0, stream>>>(P0); cur0 ^= 1;

      CellPar P1 = { hbuf + (size_t)cur0*HSZ, dWihb, hbuf + (size_t)(2+cur1)*HSZ, dWhhb,
                     nullptr, nullptr, 0, biases + 5*2048, cbuf + (size_t)HSZ,
                     hbuf + (size_t)(2+(cur1^1))*HSZ };
      cell_k<<<cgrid, cblk, 0, stream>>>(P1); cur1 ^= 1;

      const ushort* a2prev = (t == 0) ? (hbuf + (size_t)(4+1)*HSZ) : (h2hist + (size_t)(t-1)*HSZ);
      CellPar P2 = { hbuf + (size_t)(2+cur1)*HSZ, dWihb + (size_t)WSZ, a2prev, dWhhb + (size_t)WSZ,
                     nullptr, nullptr, 0, biases + 6*2048, cbuf + 2*(size_t)HSZ,
                     h2hist + (size_t)t*HSZ };
      cell_k<<<cgrid, cblk, 0, stream>>>(P2);
    }
    out_linear<<<1024, cblk, 0, stream>>>(h2hist, lin_W, lin_b, (float*)d_out);
  } else {
    for (int t = 0; t < 32; ++t){
      CellPar P0 = { hbuf + (size_t)cur0*HSZ, dWhh0b, nullptr, nullptr,
                     dec_in, dec_Wih0, 2, biases + 3*2048, cbuf, hbuf + (size_t)(cur0^1)*HSZ };
      cell_k<<<cgrid, cblk, 0, stream>>>(P0); cur0 ^= 1;

      CellPar P1 = { hbuf + (size_t)cur0*HSZ, dWihb, hbuf + (size_t)(2+cur1)*HSZ, dWhhb,
                     nullptr, nullptr, 0, biases + 5*2048, cbuf + (size_t)HSZ,
                     hbuf + (size_t)(2+(cur1^1))*HSZ };
      cell_k<<<cgrid, cblk, 0, stream>>>(P1); cur1 ^= 1;

      CellPar P2 = { hbuf + (size_t)(2+cur1)*HSZ, dWihb + (size_t)WSZ,
                     hbuf + (size_t)(4+cur2)*HSZ, dWhhb + (size_t)WSZ,
                     nullptr, nullptr, 0, biases + 6*2048, cbuf + 2*(size_t)HSZ,
                     hbuf + (size_t)(4+(cur2^1))*HSZ };
      cell_k<<<cgrid, cblk, 0, stream>>>(P2); cur2 ^= 1;

      dec_linear<<<32, cblk, 0, stream>>>(hbuf + (size_t)(4+cur2)*HSZ, lin_W, lin_b,
                                          (float*)d_out + (size_t)t*2048, dec_in);
    }
  }
}

// Round 4
// 2630.000 us; speedup vs baseline: 1.6638x; 1.6638x over previous
//
#include <hip/hip_runtime.h>
#include <hip/hip_bf16.h>

typedef __bf16 bf16x8 __attribute__((ext_vector_type(8)));
typedef float f32x4 __attribute__((ext_vector_type(4)));

#define HSZ (1024*512)      // h/c slot elems
#define WSZ (2048*512)      // weight matrix elems

__device__ __forceinline__ float fsig(float x){ return 1.0f/(1.0f+__expf(-x)); }
__device__ __forceinline__ float ftanh(float x){ return 1.0f - 2.0f/(__expf(2.0f*x)+1.0f); }

__device__ __forceinline__ void gload16(const void* g, void* l){
  __builtin_amdgcn_global_load_lds((const __attribute__((address_space(1))) void*)g,
                                   (__attribute__((address_space(3))) void*)l, 16, 0, 0);
}

// fp32 -> bf16 (RNE) converter
__global__ void f2b4(const float4* __restrict__ src, ushort4* __restrict__ dst, int n4){
  int i = blockIdx.x*blockDim.x + threadIdx.x;
  if (i < n4){
    float4 v = src[i];
    __hip_bfloat16 a=__float2bfloat16(v.x), b=__float2bfloat16(v.y), c=__float2bfloat16(v.z), d=__float2bfloat16(v.w);
    ushort4 r;
    r.x = *reinterpret_cast<ushort*>(&a);
    r.y = *reinterpret_cast<ushort*>(&b);
    r.z = *reinterpret_cast<ushort*>(&c);
    r.w = *reinterpret_cast<ushort*>(&d);
    dst[i] = r;
  }
}

__global__ void init_decin(const float* __restrict__ x, float* __restrict__ di){
  int i = blockIdx.x*blockDim.x + threadIdx.x;
  if (i < 2048){ int m = i >> 1, j = i & 1; di[i] = x[(size_t)63*4096 + m*4 + j]; }
}

// Wcomb[n][k] = dec_Wih0[n][0]*lin_W[0][k] + dec_Wih0[n][1]*lin_W[1][k]  (bf16)
__global__ void make_wcomb(const float* __restrict__ dWih0, const float* __restrict__ linW,
                           ushort* __restrict__ wc){
  int i = blockIdx.x*blockDim.x + threadIdx.x;
  if (i < 2048*512){
    int n = i >> 9, k = i & 511;
    float v = dWih0[n*2]*linW[k] + dWih0[n*2+1]*linW[512+k];
    __hip_bfloat16 b = __float2bfloat16(v);
    wc[i] = *reinterpret_cast<ushort*>(&b);
  }
}

// combined biases: rows 0-2 enc l0-l2; 3 dec l0 (t=0); 4 dec l0 (t>=1, +Wih0@lin_b); 5,6 dec l1,l2
__global__ void prep_bias(const float* ebih0, const float* ebhh0,
                          const float* ebih, const float* ebhh,
                          const float* dbih0, const float* dbhh0,
                          const float* dbih, const float* dbhh,
                          const float* dWih0, const float* linb, float* bout){
  int n = blockIdx.x*blockDim.x + threadIdx.x;
  if (n >= 2048) return;
  bout[n]        = ebih0[n] + ebhh0[n];
  bout[2048+n]   = ebih[n] + ebhh[n];
  bout[2*2048+n] = ebih[2048+n] + ebhh[2048+n];
  float d0 = dbih0[n] + dbhh0[n];
  bout[3*2048+n] = d0;
  bout[4*2048+n] = d0 + dWih0[n*2]*linb[0] + dWih0[n*2+1]*linb[1];
  bout[5*2048+n] = dbih[n] + dbhh[n];
  bout[6*2048+n] = dbih[2048+n] + dbhh[2048+n];
}

struct CellPar {
  const ushort* A0; const ushort* W0;   // bf16 segment 0 (A:[1024][512], W:[2048][512])
  const ushort* A1; const ushort* W1;   // bf16 segment 1 (null if absent)
  const float*  xs; const float* Ws; int ks;  // small-K fp32 part
  const float*  bias;                   // combined bias [2048]
  float* c; ushort* h_out;
};

// WG tile: 64 batch x 128 gate-rows (= 4 gates x 32 h), grid 256 (remapped).
// B LDS row r <-> weight row ((r>>4)&3)*512 + h0 + (r>>6)*16 + (r&15)
//   (each 64-row half holds all 4 gates at 16 h -> gate gather stays in-register).
// 4 waves = 2(batch:wm) x 2(h-half:wn); wave tile 32 batch x 64 gate-rows:
//   per kh: 2 av + 4 bv reads -> 8 MFMA (16x16x32).
// 2-phase dbuf (24KB each), counted vmcnt(6), pre-swizzled source + XOR-swizzled reads.
__device__ __forceinline__ void cell_body(const CellPar P, char* ldsb, int m0, int h0)
{
  const int tid  = threadIdx.x;
  const int w    = tid >> 6, lane = tid & 63;
  const int wm   = w >> 1, wn = w & 1;
  const int colL = lane & 15, kgrp = lane >> 4;
  const int srow = lane >> 3, scch = lane & 7;

  const ushort* Aseg[2] = { P.A0, P.A1 };
  const ushort* Wseg[2] = { P.W0, P.W1 };
  const int nt = (P.A1 != nullptr) ? 16 : 8;   // K-steps of 64 (8 per 512-K segment)

  auto stage = [&](int buf, int it){
    const int seg = it >> 3;
    const int k0  = (it & 7) << 6;
    const ushort* A  = Aseg[seg];
    const ushort* Wt = Wseg[seg];
    ushort* Als = (ushort*)(ldsb + buf*24576);
    ushort* Bls = Als + 4096;                   // +8KB
    #pragma unroll
    for (int q = 0; q < 2; ++q){                // A: 64 rows, 2 instr/wave
      const int base = (w<<4) + (q<<3);
      const int r  = base + srow;
      const int sw = (scch ^ (r & 7)) << 3;     // pre-swizzled source chunk
      gload16(A + (size_t)(m0 + r)*512 + k0 + sw, Als + base*64);
    }
    #pragma unroll
    for (int q = 0; q < 4; ++q){                // B: 128 rows, 4 instr/wave
      const int base = (w<<5) + (q<<3);
      const int r  = base + srow;
      const int g = (r >> 4) & 3, hp = r >> 6, hh = r & 15;
      const int sw = (scch ^ (r & 7)) << 3;
      gload16(Wt + ((size_t)(g<<9) + h0 + (hp<<4) + hh)*512 + k0 + sw, Bls + base*64);
    }
  };

  f32x4 acc[2][4] = {};

  stage(0, 0);
  for (int it = 0; it < nt; ++it){
    const int cur = it & 1;
    if (it + 1 < nt) stage(cur ^ 1, it + 1);
    __builtin_amdgcn_sched_barrier(0);
    if (it + 1 < nt) asm volatile("s_waitcnt vmcnt(6)" ::: "memory");
    else             asm volatile("s_waitcnt vmcnt(0)" ::: "memory");
    __builtin_amdgcn_s_barrier();                  // all waves' stage(it) landed
    __builtin_amdgcn_sched_barrier(0);
    const ushort* Als = (const ushort*)(ldsb + cur*24576);
    const ushort* Bls = Als + 4096;
    const int ar0 = (wm<<5) + colL;
    const int ar1 = ar0 + 16;
    __builtin_amdgcn_s_setprio(1);
    #pragma unroll
    for (int kh = 0; kh < 2; ++kh){
      const int cb = (kh<<2) + kgrp;
      bf16x8 av0 = *(const bf16x8*)(Als + ar0*64 + ((cb ^ (ar0 & 7)) << 3));
      bf16x8 av1 = *(const bf16x8*)(Als + ar1*64 + ((cb ^ (ar1 & 7)) << 3));
      #pragma unroll
      for (int nf = 0; nf < 4; ++nf){
        const int br = (wn<<6) + (nf<<4) + colL;
        bf16x8 bv = *(const bf16x8*)(Bls + br*64 + ((cb ^ (br & 7)) << 3));
        acc[0][nf] = __builtin_amdgcn_mfma_f32_16x16x32_bf16(av0, bv, acc[0][nf], 0, 0, 0);
        acc[1][nf] = __builtin_amdgcn_mfma_f32_16x16x32_bf16(av1, bv, acc[1][nf], 0, 0, 0);
      }
    }
    __builtin_amdgcn_s_setprio(0);
    __builtin_amdgcn_sched_barrier(0);
    __builtin_amdgcn_s_barrier();                  // reads done before buffer reuse
  }

  // ---- epilogue (gate index = nf, purely in-register) ----
  const int h = h0 + (wn<<4) + colL;
  float bia[4], wsv[4][4];
  #pragma unroll
  for (int g = 0; g < 4; ++g) bia[g] = P.bias[(g<<9) + h];
  if (P.ks > 0){
    #pragma unroll
    for (int g = 0; g < 4; ++g)
      #pragma unroll
      for (int k = 0; k < 4; ++k)
        wsv[g][k] = (k < P.ks) ? P.Ws[(size_t)((g<<9) + h)*P.ks + k] : 0.f;
  }

  #pragma unroll
  for (int mf = 0; mf < 2; ++mf){
    const int mB = m0 + (wm<<5) + (mf<<4) + (kgrp<<2);
    float xv[4][4];
    if (P.ks > 0){
      #pragma unroll
      for (int r = 0; r < 4; ++r)
        #pragma unroll
        for (int k = 0; k < 4; ++k)
          xv[r][k] = (k < P.ks) ? P.xs[(size_t)(mB + r)*P.ks + k] : 0.f;
    }
    #pragma unroll
    for (int r = 0; r < 4; ++r){
      const int m = mB + r;
      float gv[4];
      #pragma unroll
      for (int g = 0; g < 4; ++g){
        float t_ = acc[mf][g][r] + bia[g];
        if (P.ks > 0){
          #pragma unroll
          for (int k = 0; k < 4; ++k) t_ += xv[r][k]*wsv[g][k];
        }
        gv[g] = t_;
      }
      const float iG = fsig(gv[0]);
      const float fG = fsig(gv[1]);
      const float gG = ftanh(gv[2]);
      const float oG = fsig(gv[3]);
      const size_t off = (size_t)m*512 + h;
      const float cn = fG*P.c[off] + iG*gG;
      P.c[off] = cn;
      const float hv = oG*ftanh(cn);
      __hip_bfloat16 hb = __float2bfloat16(hv);
      P.h_out[off] = *reinterpret_cast<const ushort*>(&hb);
    }
  }
}

// grid 256 (1-D): XCD-chunked remap so all 16 batch-blocks of a weight tile
// share one XCD (weight tile -> single L2, stays resident across steps).
__global__ __launch_bounds__(256) void cell_k(CellPar P){
  __shared__ char lds[49152];
  const int f = blockIdx.x;
  const int xcd = f & 7, j = f >> 3;          // j 0..31
  const int bx = j & 15;
  const int by = ((j >> 4) << 3) + xcd;       // {xcd, 8+xcd}
  cell_body(P, lds, bx << 6, by << 5);
}

struct EncPack {
  const float* x; const float* Wih0f;
  const ushort* eWhh0; const ushort* eWih; const ushort* eWhh;
  const float* biases; ushort* hbuf; float* cbuf; int s;
};

// fused encoder wavefront step: grid 768 (1-D), XCD remap; yz = i*8+xcd keeps
// each (h-tile,layer) on one XCD AND balances layer-0 (nt=8) across XCDs.
__global__ __launch_bounds__(256) void enc_step(EncPack E){
  __shared__ char lds[49152];
  const int f = blockIdx.x;
  const int xcd = f & 7, j = f >> 3;          // j 0..95
  const int bx = j & 15;
  const int yz = ((j >> 4) << 3) + xcd;       // 0..47
  const int by = yz & 15, l = yz >> 4;
  const int t = E.s - l;
  if (t < 0 || t > 63) return;
  const int p = E.s & 1;
  CellPar P;
  if (l == 0){
    P = { E.hbuf + (size_t)(p^1)*HSZ, E.eWhh0,
          nullptr, nullptr,
          E.x + (size_t)t*4096, E.Wih0f, 4,
          E.biases, E.cbuf, E.hbuf + (size_t)p*HSZ };
  } else {
    P = { E.hbuf + (size_t)(2*(l-1) + (p^1))*HSZ, E.eWih + (size_t)(l-1)*WSZ,
          E.hbuf + (size_t)(2*l + (p^1))*HSZ,     E.eWhh + (size_t)(l-1)*WSZ,
          nullptr, nullptr, 0,
          E.biases + l*2048, E.cbuf + (size_t)l*HSZ, E.hbuf + (size_t)(2*l + p)*HSZ };
  }
  cell_body(P, lds, bx << 6, by << 5);
}

// batched final linear over all 32 steps: rows = 32*1024
__global__ __launch_bounds__(256) void out_linear(const ushort* __restrict__ h2,
    const float* __restrict__ linW, const float* __restrict__ linb, float* __restrict__ outp){
  int tid = threadIdx.x, w = tid >> 6, lane = tid & 63;
  int rbase = blockIdx.x*32 + w*8;
  for (int r = 0; r < 8; ++r){
    int m = rbase + r;
    float p0 = 0.f, p1 = 0.f;
    #pragma unroll
    for (int kk = 0; kk < 8; ++kk){
      int k = lane + kk*64;
      float hv = __uint_as_float(((unsigned)h2[(size_t)m*512 + k]) << 16);
      p0 += hv * linW[k];
      p1 += hv * linW[512 + k];
    }
    #pragma unroll
    for (int off = 32; off > 0; off >>= 1){
      p0 += __shfl_down(p0, off);
      p1 += __shfl_down(p1, off);
    }
    if (lane == 0){
      outp[(size_t)m*2]   = p0 + linb[0];
      outp[(size_t)m*2+1] = p1 + linb[1];
    }
  }
}

// fallback per-step linear (small-ws path): writes out slice + dec_in
__global__ __launch_bounds__(256) void dec_linear(const ushort* __restrict__ h2,
    const float* __restrict__ linW, const float* __restrict__ linb,
    float* __restrict__ outp, float* __restrict__ di){
  int tid = threadIdx.x, w = tid >> 6, lane = tid & 63;
  int mbase = blockIdx.x*32 + w*8;
  for (int r = 0; r < 8; ++r){
    int m = mbase + r;
    float p0 = 0.f, p1 = 0.f;
    #pragma unroll
    for (int kk = 0; kk < 8; ++kk){
      int k = lane + kk*64;
      float hv = __uint_as_float(((unsigned)h2[(size_t)m*512 + k]) << 16);
      p0 += hv * linW[k];
      p1 += hv * linW[512 + k];
    }
    #pragma unroll
    for (int off = 32; off > 0; off >>= 1){
      p0 += __shfl_down(p0, off);
      p1 += __shfl_down(p1, off);
    }
    if (lane == 0){
      float o0 = p0 + linb[0], o1 = p1 + linb[1];
      outp[m*2]   = o0; outp[m*2+1] = o1;
      di[m*2]     = o0; di[m*2+1]   = o1;
    }
  }
}

extern "C" void kernel_launch(void* const* d_in, const int* in_sizes, int n_in,
                              void* d_out, int out_size, void* d_ws, size_t ws_size,
                              hipStream_t stream)
{
  const float* x        = (const float*)d_in[0];
  const float* enc_Wih0 = (const float*)d_in[1];
  const float* enc_Whh0 = (const float*)d_in[2];
  const float* enc_bih0 = (const float*)d_in[3];
  const float* enc_bhh0 = (const float*)d_in[4];
  const float* enc_Wih  = (const float*)d_in[5];
  const float* enc_Whh  = (const float*)d_in[6];
  const float* enc_bih  = (const float*)d_in[7];
  const float* enc_bhh  = (const float*)d_in[8];
  const float* dec_Wih0 = (const float*)d_in[9];
  const float* dec_Whh0 = (const float*)d_in[10];
  const float* dec_bih0 = (const float*)d_in[11];
  const float* dec_bhh0 = (const float*)d_in[12];
  const float* dec_Wih  = (const float*)d_in[13];
  const float* dec_Whh  = (const float*)d_in[14];
  const float* dec_bih  = (const float*)d_in[15];
  const float* dec_bhh  = (const float*)d_in[16];
  const float* lin_W    = (const float*)d_in[17];
  const float* lin_b    = (const float*)d_in[18];

  // big path needs: 2*(11W + 6HS + 32HS) + 4*(3HS + 2048 + 7*2048) bytes = 69,271,552
  const bool big = ws_size >= 69271552ull;

  ushort* wb     = (ushort*)d_ws;
  ushort* eWhh0b = wb;
  ushort* eWihb  = wb + (size_t)WSZ;
  ushort* eWhhb  = wb + 3*(size_t)WSZ;
  ushort* dWhh0b = wb + 5*(size_t)WSZ;
  ushort* dWihb  = wb + 6*(size_t)WSZ;
  ushort* dWhhb  = wb + 8*(size_t)WSZ;
  ushort* wcombb = wb + 10*(size_t)WSZ;                   // big only
  ushort* hbuf   = wb + (big ? 11 : 10)*(size_t)WSZ;      // 6 HSZ (3 layers x 2 slots)
  ushort* h2hist = hbuf + 6*(size_t)HSZ;                  // big: 32 HSZ
  float*  cbuf   = (float*)(h2hist + (big ? 32*(size_t)HSZ : 0));
  float*  dec_in = cbuf + 3*(size_t)HSZ;                  // 2048
  float*  biases = dec_in + 2048;                         // 7*2048

  hipMemsetAsync(hbuf, 0, 6*(size_t)HSZ*2, stream);
  hipMemsetAsync(cbuf, 0, 3*(size_t)HSZ*4, stream);

  const int thr = 256;
  {
    struct { const float* s; ushort* d; size_t n; } cv[6] = {
      {enc_Whh0, eWhh0b, WSZ}, {enc_Wih, eWihb, 2*(size_t)WSZ}, {enc_Whh, eWhhb, 2*(size_t)WSZ},
      {dec_Whh0, dWhh0b, WSZ}, {dec_Wih, dWihb, 2*(size_t)WSZ}, {dec_Whh, dWhhb, 2*(size_t)WSZ},
    };
    for (int i = 0; i < 6; ++i){
      int n4 = (int)(cv[i].n/4);
      f2b4<<<(n4+thr-1)/thr, thr, 0, stream>>>((const float4*)cv[i].s, (ushort4*)cv[i].d, n4);
    }
  }
  if (big) make_wcomb<<<4096, thr, 0, stream>>>(dec_Wih0, lin_W, wcombb);
  prep_bias<<<8, thr, 0, stream>>>(enc_bih0, enc_bhh0, enc_bih, enc_bhh,
                                   dec_bih0, dec_bhh0, dec_bih, dec_bhh,
                                   dec_Wih0, lin_b, biases);
  init_decin<<<8, thr, 0, stream>>>(x, dec_in);

  const dim3 cblk(256);

  // ---- encoder: fused wavefront steps ----
  for (int s = 0; s < 66; ++s){
    EncPack E = { x, enc_Wih0, eWhh0b, eWihb, eWhhb, biases, hbuf, cbuf, s };
    enc_step<<<768, cblk, 0, stream>>>(E);
  }

  // encoder-final slots: layer l written at step 63+l -> slot (63+l)&1
  int cur0 = 1, cur1 = 0, cur2 = 1;

  if (big){
    for (int t = 0; t < 32; ++t){
      CellPar P0;
      if (t == 0)
        P0 = { hbuf + (size_t)cur0*HSZ, dWhh0b, nullptr, nullptr,
               dec_in, dec_Wih0, 2, biases + 3*2048, cbuf, hbuf + (size_t)(cur0^1)*HSZ };
      else
        P0 = { h2hist + (size_t)(t-1)*HSZ, wcombb, hbuf + (size_t)cur0*HSZ, dWhh0b,
               nullptr, nullptr, 0, biases + 4*2048, cbuf, hbuf + (size_t)(cur0^1)*HSZ };
      cell_k<<<256, cblk, 0, stream>>>(P0); cur0 ^= 1;

      CellPar P1 = { hbuf + (size_t)cur0*HSZ, dWihb, hbuf + (size_t)(2+cur1)*HSZ, dWhhb,
                     nullptr, nullptr, 0, biases + 5*2048, cbuf + (size_t)HSZ,
                     hbuf + (size_t)(2+(cur1^1))*HSZ };
      cell_k<<<256, cblk, 0, stream>>>(P1); cur1 ^= 1;

      const ushort* a2prev = (t == 0) ? (hbuf + (size_t)(4+1)*HSZ) : (h2hist + (size_t)(t-1)*HSZ);
      CellPar P2 = { hbuf + (size_t)(2+cur1)*HSZ, dWihb + (size_t)WSZ, a2prev, dWhhb + (size_t)WSZ,
                     nullptr, nullptr, 0, biases + 6*2048, cbuf + 2*(size_t)HSZ,
                     h2hist + (size_t)t*HSZ };
      cell_k<<<256, cblk, 0, stream>>>(P2);
    }
    out_linear<<<1024, cblk, 0, stream>>>(h2hist, lin_W, lin_b, (float*)d_out);
  } else {
    for (int t = 0; t < 32; ++t){
      CellPar P0 = { hbuf + (size_t)cur0*HSZ, dWhh0b, nullptr, nullptr,
                     dec_in, dec_Wih0, 2, biases + 3*2048, cbuf, hbuf + (size_t)(cur0^1)*HSZ };
      cell_k<<<256, cblk, 0, stream>>>(P0); cur0 ^= 1;

      CellPar P1 = { hbuf + (size_t)cur0*HSZ, dWihb, hbuf + (size_t)(2+cur1)*HSZ, dWhhb,
                     nullptr, nullptr, 0, biases + 5*2048, cbuf + (size_t)HSZ,
                     hbuf + (size_t)(2+(cur1^1))*HSZ };
      cell_k<<<256, cblk, 0, stream>>>(P1); cur1 ^= 1;

      CellPar P2 = { hbuf + (size_t)(2+cur1)*HSZ, dWihb + (size_t)WSZ,
                     hbuf + (size_t)(4+cur2)*HSZ, dWhhb + (size_t)WSZ,
                     nullptr, nullptr, 0, biases + 6*2048, cbuf + 2*(size_t)HSZ,
                     hbuf + (size_t)(4+(cur2^1))*HSZ };
      cell_k<<<256, cblk, 0, stream>>>(P2); cur2 ^= 1;

      dec_linear<<<32, cblk, 0, stream>>>(hbuf + (size_t)(4+cur2)*HSZ, lin_W, lin_b,
                                          (float*)d_out + (size_t)t*2048, dec_in);
    }
  }
}